// Round 1
// baseline (729.955 us; speedup 1.0000x reference)
//
#include <hip/hip_runtime.h>
#include <cstdint>
#include <cstddef>

#define NB 32
#define NN 1024
#define ND 256
#define KNNK 16

// ---------------------------------------------------------------------------
// Kernel A: fused positional-add + dual projection GEMM.
//   Q [B*N, 256] row-major,  Kt [B, 256, 1024]  (K transposed per batch)
// Tile: 64 rows x 64 cols, 256 threads (16x16), 4x4 microtile, K-chunk 16.
// ---------------------------------------------------------------------------
__global__ __launch_bounds__(256) void proj_kernel(
    const float* __restrict__ x, const float* __restrict__ pos,
    const float* __restrict__ wq, const float* __restrict__ bq,
    const float* __restrict__ wk, const float* __restrict__ bk,
    float* __restrict__ Qg, float* __restrict__ Ktg)
{
    __shared__ __align__(16) float Hs[16][64];
    __shared__ __align__(16) float Ws[16][64];

    const int tid = threadIdx.x;
    const int tx = tid & 15;
    const int ty = tid >> 4;
    const int bm = blockIdx.x >> 3;   // 0..511 row tiles
    const int be = blockIdx.x & 7;    // 0..7 col tiles (0-3 -> Q, 4-7 -> K)
    const int rowBase = bm << 6;
    const int b  = rowBase >> 10;
    const int n0 = rowBase & 1023;
    const int eBase = be << 6;
    const bool isQ = (eBase < 256);
    const float* __restrict__ W    = isQ ? wq : wk;
    const float* __restrict__ bias = isQ ? bq : bk;
    const int e0 = isQ ? eBase : (eBase - 256);

    const int sr = tid >> 2;          // 0..63 (row / col index for staging)
    const int sd = (tid & 3) << 2;    // 0,4,8,12

    float acc[4][4];
    #pragma unroll
    for (int i = 0; i < 4; ++i)
        #pragma unroll
        for (int j = 0; j < 4; ++j) acc[i][j] = 0.0f;

    #pragma unroll 1
    for (int dc = 0; dc < 256; dc += 16) {
        const float4 xv = *(const float4*)&x[(size_t)(rowBase + sr) * 256 + dc + sd];
        const float4 pv = *(const float4*)&pos[(size_t)(n0 + sr) * 256 + dc + sd];
        const float4 wv = *(const float4*)&W[(size_t)(e0 + sr) * 256 + dc + sd];
        __syncthreads();   // previous compute done reading LDS
        Hs[sd + 0][sr] = xv.x + pv.x;
        Hs[sd + 1][sr] = xv.y + pv.y;
        Hs[sd + 2][sr] = xv.z + pv.z;
        Hs[sd + 3][sr] = xv.w + pv.w;
        Ws[sd + 0][sr] = wv.x;
        Ws[sd + 1][sr] = wv.y;
        Ws[sd + 2][sr] = wv.z;
        Ws[sd + 3][sr] = wv.w;
        __syncthreads();
        #pragma unroll
        for (int d = 0; d < 16; ++d) {
            const float4 av = *(const float4*)&Hs[d][ty << 2];
            const float4 bv = *(const float4*)&Ws[d][tx << 2];
            const float a4[4] = {av.x, av.y, av.z, av.w};
            const float b4[4] = {bv.x, bv.y, bv.z, bv.w};
            #pragma unroll
            for (int i = 0; i < 4; ++i)
                #pragma unroll
                for (int j = 0; j < 4; ++j)
                    acc[i][j] = fmaf(a4[i], b4[j], acc[i][j]);
        }
    }

    const float4 bv4 = *(const float4*)&bias[e0 + (tx << 2)];
    const float bb[4] = {bv4.x, bv4.y, bv4.z, bv4.w};
    #pragma unroll
    for (int i = 0; i < 4; ++i)
        #pragma unroll
        for (int j = 0; j < 4; ++j) acc[i][j] += bb[j];

    if (isQ) {
        #pragma unroll
        for (int i = 0; i < 4; ++i) {
            float4 o;
            o.x = acc[i][0]; o.y = acc[i][1]; o.z = acc[i][2]; o.w = acc[i][3];
            *(float4*)&Qg[(size_t)(rowBase + (ty << 2) + i) * 256 + eBase + (tx << 2)] = o;
        }
    } else {
        #pragma unroll
        for (int j = 0; j < 4; ++j)
            #pragma unroll
            for (int i = 0; i < 4; ++i)
                Ktg[((size_t)(b * 256) + e0 + (tx << 2) + j) * 1024 + n0 + (ty << 2) + i]
                    = acc[i][j];
    }
}

// ---------------------------------------------------------------------------
// Kernel B: scores (Q @ K^T / 16) + softmax + top-16 sparsify, fused.
// One WG = (batch b, 32 rows). 4 waves x 8 rows, acc[8][16] per lane.
// Column mapping per lane: m = 4*lane + 256*o + i  (slot = 4*o + i).
// ---------------------------------------------------------------------------
__global__ __launch_bounds__(256, 2) void adj_topk_kernel(
    const float* __restrict__ Qg, const float* __restrict__ Ktg,
    float* __restrict__ out)
{
    __shared__ __align__(16) float Ks[8][1024];
    __shared__ __align__(16) float Qc[32][8];

    const int tid  = threadIdx.x;
    const int lane = tid & 63;
    const int w    = tid >> 6;
    const int b       = blockIdx.x >> 5;
    const int rowBase = (blockIdx.x & 31) << 5;

    const float* __restrict__ Qb = Qg  + ((size_t)(b * 1024 + rowBase)) * 256;
    const float* __restrict__ Kb = Ktg + (size_t)b * (256 * 1024);

    float acc[8][16];
    #pragma unroll
    for (int r = 0; r < 8; ++r)
        #pragma unroll
        for (int i = 0; i < 16; ++i) acc[r][i] = 0.0f;

    #pragma unroll 1
    for (int dc = 0; dc < 256; dc += 8) {
        float4 kreg[8];
        #pragma unroll
        for (int k = 0; k < 8; ++k)
            kreg[k] = *(const float4*)&Kb[(size_t)(dc + k) * 1024 + (tid << 2)];
        float4 qreg;
        if (tid < 64)
            qreg = *(const float4*)&Qb[(size_t)(tid >> 1) * 256 + dc + ((tid & 1) << 2)];
        __syncthreads();   // previous compute done reading LDS
        #pragma unroll
        for (int k = 0; k < 8; ++k)
            *(float4*)&Ks[k][tid << 2] = kreg[k];
        if (tid < 64) {
            const int rr = tid >> 1, dd = (tid & 1) << 2;
            Qc[rr][dd + 0] = qreg.x;
            Qc[rr][dd + 1] = qreg.y;
            Qc[rr][dd + 2] = qreg.z;
            Qc[rr][dd + 3] = qreg.w;
        }
        __syncthreads();
        #pragma unroll
        for (int d = 0; d < 8; ++d) {
            const float4 kt0 = *(const float4*)&Ks[d][(lane << 2)];
            const float4 kt1 = *(const float4*)&Ks[d][(lane << 2) + 256];
            const float4 kt2 = *(const float4*)&Ks[d][(lane << 2) + 512];
            const float4 kt3 = *(const float4*)&Ks[d][(lane << 2) + 768];
            #pragma unroll
            for (int r = 0; r < 8; ++r) {
                const float q = Qc[(w << 3) + r][d];
                acc[r][0]  = fmaf(q, kt0.x, acc[r][0]);
                acc[r][1]  = fmaf(q, kt0.y, acc[r][1]);
                acc[r][2]  = fmaf(q, kt0.z, acc[r][2]);
                acc[r][3]  = fmaf(q, kt0.w, acc[r][3]);
                acc[r][4]  = fmaf(q, kt1.x, acc[r][4]);
                acc[r][5]  = fmaf(q, kt1.y, acc[r][5]);
                acc[r][6]  = fmaf(q, kt1.z, acc[r][6]);
                acc[r][7]  = fmaf(q, kt1.w, acc[r][7]);
                acc[r][8]  = fmaf(q, kt2.x, acc[r][8]);
                acc[r][9]  = fmaf(q, kt2.y, acc[r][9]);
                acc[r][10] = fmaf(q, kt2.z, acc[r][10]);
                acc[r][11] = fmaf(q, kt2.w, acc[r][11]);
                acc[r][12] = fmaf(q, kt3.x, acc[r][12]);
                acc[r][13] = fmaf(q, kt3.y, acc[r][13]);
                acc[r][14] = fmaf(q, kt3.z, acc[r][14]);
                acc[r][15] = fmaf(q, kt3.w, acc[r][15]);
            }
        }
    }

    const int row0 = rowBase + (w << 3);

    // ---- zero pass: full coverage of all 8 rows (d_out poisoned per run) ----
    const float4 z4 = make_float4(0.f, 0.f, 0.f, 0.f);
    #pragma unroll
    for (int r = 0; r < 8; ++r) {
        float* orow = out + ((size_t)(b * 1024 + row0 + r)) * 1024;
        *(float4*)&orow[(lane << 2)      ] = z4;
        *(float4*)&orow[(lane << 2) + 256] = z4;
        *(float4*)&orow[(lane << 2) + 512] = z4;
        *(float4*)&orow[(lane << 2) + 768] = z4;
    }
    // drain the zero stores before scatter-writing values into the same rows
    asm volatile("s_waitcnt vmcnt(0)" ::: "memory");

    #pragma unroll
    for (int r = 0; r < 8; ++r) {
        float* orow = out + ((size_t)(b * 1024 + row0 + r)) * 1024;
        float s[16];
        #pragma unroll
        for (int i = 0; i < 16; ++i) s[i] = acc[r][i] * 0.0625f;

        // row max (wave butterfly)
        float mx = s[0];
        #pragma unroll
        for (int i = 1; i < 16; ++i) mx = fmaxf(mx, s[i]);
        #pragma unroll
        for (int off = 32; off > 0; off >>= 1)
            mx = fmaxf(mx, __shfl_xor(mx, off));

        // softmax denominator
        float ls = 0.f;
        #pragma unroll
        for (int i = 0; i < 16; ++i) ls += __expf(s[i] - mx);
        #pragma unroll
        for (int off = 32; off > 0; off >>= 1)
            ls += __shfl_xor(ls, off);
        const float Z = ls;

        // top-16 extraction; key = (monotonic(val) << 32) | ~m
        // -> max value wins, exact ties -> smaller m (matches jax.lax.top_k)
        #pragma unroll 1
        for (int j = 0; j < KNNK; ++j) {
            float bv  = s[0];
            int   bmi = (lane << 2);
            #pragma unroll
            for (int i = 1; i < 16; ++i) {
                const int mi = ((i >> 2) << 8) + (lane << 2) + (i & 3);
                const bool c = s[i] > bv;   // strict >, ascending m scan
                bv  = c ? s[i] : bv;
                bmi = c ? mi   : bmi;
            }
            const unsigned ub   = __float_as_uint(bv);
            const unsigned mono = ub ^ (unsigned)(((int)ub >> 31) | 0x80000000);
            const unsigned long long key =
                ((unsigned long long)mono << 32) | (unsigned)(~bmi);
            unsigned long long gk = key;
            #pragma unroll
            for (int off = 32; off > 0; off >>= 1) {
                const unsigned long long o = __shfl_xor(gk, off);
                gk = (o > gk) ? o : gk;
            }
            if (key == gk) {   // unique winner lane
                const float p = __expf(bv - mx) / Z;
                orow[bmi] = p;
                const int slot = ((bmi >> 8) << 2) | (bmi & 3);
                #pragma unroll
                for (int i = 0; i < 16; ++i)
                    s[i] = (i == slot) ? -__builtin_inff() : s[i];
            }
        }
    }
}

extern "C" void kernel_launch(void* const* d_in, const int* in_sizes, int n_in,
                              void* d_out, int out_size, void* d_ws, size_t ws_size,
                              hipStream_t stream)
{
    const float* x   = (const float*)d_in[0];
    const float* pos = (const float*)d_in[1];
    const float* wq  = (const float*)d_in[2];
    const float* bq  = (const float*)d_in[3];
    const float* wk  = (const float*)d_in[4];
    const float* bk  = (const float*)d_in[5];
    float* out = (float*)d_out;

    float* Qg  = (float*)d_ws;                    // 32 MB: [B*N, 256]
    float* Ktg = Qg + (size_t)NB * NN * ND;       // 32 MB: [B, 256, 1024]

    proj_kernel<<<dim3(4096), dim3(256), 0, stream>>>(x, pos, wq, bq, wk, bk, Qg, Ktg);
    adj_topk_kernel<<<dim3(1024), dim3(256), 0, stream>>>(Qg, Ktg, out);
}

// Round 2
// 526.855 us; speedup vs baseline: 1.3855x; 1.3855x over previous
//
#include <hip/hip_runtime.h>
#include <cstdint>
#include <cstddef>

#define NB 32
#define NN 1024
#define ND 256
#define KNNK 16

// ---------------------------------------------------------------------------
// Kernel A: fused positional-add + dual projection GEMM.
//   Q [B*N, 256] row-major,  Kt [B, 256, 1024]  (K transposed per batch)
// Tile: 64 rows x 64 cols, 256 threads (16x16), 4x4 microtile, K-chunk 16.
// (measured ~55 us ~= fp32 vector roofline for 8.6 GFLOP; unchanged)
// ---------------------------------------------------------------------------
__global__ __launch_bounds__(256) void proj_kernel(
    const float* __restrict__ x, const float* __restrict__ pos,
    const float* __restrict__ wq, const float* __restrict__ bq,
    const float* __restrict__ wk, const float* __restrict__ bk,
    float* __restrict__ Qg, float* __restrict__ Ktg)
{
    __shared__ __align__(16) float Hs[16][64];
    __shared__ __align__(16) float Ws[16][64];

    const int tid = threadIdx.x;
    const int tx = tid & 15;
    const int ty = tid >> 4;
    const int bm = blockIdx.x >> 3;   // 0..511 row tiles
    const int be = blockIdx.x & 7;    // 0..7 col tiles (0-3 -> Q, 4-7 -> K)
    const int rowBase = bm << 6;
    const int b  = rowBase >> 10;
    const int n0 = rowBase & 1023;
    const int eBase = be << 6;
    const bool isQ = (eBase < 256);
    const float* __restrict__ W    = isQ ? wq : wk;
    const float* __restrict__ bias = isQ ? bq : bk;
    const int e0 = isQ ? eBase : (eBase - 256);

    const int sr = tid >> 2;          // 0..63 (row / col index for staging)
    const int sd = (tid & 3) << 2;    // 0,4,8,12

    float acc[4][4];
    #pragma unroll
    for (int i = 0; i < 4; ++i)
        #pragma unroll
        for (int j = 0; j < 4; ++j) acc[i][j] = 0.0f;

    #pragma unroll 1
    for (int dc = 0; dc < 256; dc += 16) {
        const float4 xv = *(const float4*)&x[(size_t)(rowBase + sr) * 256 + dc + sd];
        const float4 pv = *(const float4*)&pos[(size_t)(n0 + sr) * 256 + dc + sd];
        const float4 wv = *(const float4*)&W[(size_t)(e0 + sr) * 256 + dc + sd];
        __syncthreads();   // previous compute done reading LDS
        Hs[sd + 0][sr] = xv.x + pv.x;
        Hs[sd + 1][sr] = xv.y + pv.y;
        Hs[sd + 2][sr] = xv.z + pv.z;
        Hs[sd + 3][sr] = xv.w + pv.w;
        Ws[sd + 0][sr] = wv.x;
        Ws[sd + 1][sr] = wv.y;
        Ws[sd + 2][sr] = wv.z;
        Ws[sd + 3][sr] = wv.w;
        __syncthreads();
        #pragma unroll
        for (int d = 0; d < 16; ++d) {
            const float4 av = *(const float4*)&Hs[d][ty << 2];
            const float4 bv = *(const float4*)&Ws[d][tx << 2];
            const float a4[4] = {av.x, av.y, av.z, av.w};
            const float b4[4] = {bv.x, bv.y, bv.z, bv.w};
            #pragma unroll
            for (int i = 0; i < 4; ++i)
                #pragma unroll
                for (int j = 0; j < 4; ++j)
                    acc[i][j] = fmaf(a4[i], b4[j], acc[i][j]);
        }
    }

    const float4 bv4 = *(const float4*)&bias[e0 + (tx << 2)];
    const float bb[4] = {bv4.x, bv4.y, bv4.z, bv4.w};
    #pragma unroll
    for (int i = 0; i < 4; ++i)
        #pragma unroll
        for (int j = 0; j < 4; ++j) acc[i][j] += bb[j];

    if (isQ) {
        #pragma unroll
        for (int i = 0; i < 4; ++i) {
            float4 o;
            o.x = acc[i][0]; o.y = acc[i][1]; o.z = acc[i][2]; o.w = acc[i][3];
            *(float4*)&Qg[(size_t)(rowBase + (ty << 2) + i) * 256 + eBase + (tx << 2)] = o;
        }
    } else {
        #pragma unroll
        for (int j = 0; j < 4; ++j)
            #pragma unroll
            for (int i = 0; i < 4; ++i)
                Ktg[((size_t)(b * 256) + e0 + (tx << 2) + j) * 1024 + n0 + (ty << 2) + i]
                    = acc[i][j];
    }
}

// ---------------------------------------------------------------------------
// Kernel B v2: scores (Q @ K^T / 16) + softmax + top-16 sparsify, fused.
// One WG = (batch b, 32 rows). 4 waves x 8 rows, acc[8][16] per lane.
// Column mapping per lane: m = 4*lane + 256*o + (i&3), slot i = 4*o + (i&3).
//
// v2 changes vs v1 (latency-bound, VALUBusy 36%):
//  - NO barriers in main loop: K streamed from global (L2-resident, Kt[b]=1MB
//    fits per-XCD L2), register ping-pong prefetch one 2-d chunk ahead.
//  - Q tile loaded to LDS once; broadcast ds_read_b64 per row (no conflicts).
//  - Epilogue: selection bitmask + single full-coverage coalesced write pass
//    (kills the zero-pass + vmcnt(0) drain + RMW scatter: 1.1GB -> 134MB).
// ---------------------------------------------------------------------------
__global__ __launch_bounds__(256, 2) void adj_topk_kernel(
    const float* __restrict__ Qg, const float* __restrict__ Ktg,
    float* __restrict__ out)
{
    __shared__ __align__(16) float Qc[32][256];   // 32 KB

    const int tid  = threadIdx.x;
    const int lane = tid & 63;
    const int w    = tid >> 6;
    const int b       = blockIdx.x >> 5;
    const int rowBase = (blockIdx.x & 31) << 5;

    const float* __restrict__ Qb = Qg  + ((size_t)(b * 1024 + rowBase)) * 256;
    const float* __restrict__ Kb = Ktg + (size_t)b * (256 * 1024);

    // ---- stage Q tile (32 rows x 256) into LDS, once ----
    #pragma unroll
    for (int j = 0; j < 8; ++j) {
        const int idx = tid + (j << 8);          // 0..2047
        const int r  = idx >> 6;
        const int c4 = (idx & 63) << 2;
        *(float4*)&Qc[r][c4] = *(const float4*)&Qb[(size_t)r * 256 + c4];
    }
    __syncthreads();

    float acc[8][16];
    #pragma unroll
    for (int r = 0; r < 8; ++r)
        #pragma unroll
        for (int i = 0; i < 16; ++i) acc[r][i] = 0.0f;

    const int row0 = w << 3;                     // wave's first local row
    const float* __restrict__ kp = Kb + (lane << 2);

    // ---- prefetch chunk 0 (d = 0, 1) ----
    float4 kc[8];
    #pragma unroll
    for (int q = 0; q < 4; ++q) {
        kc[q]     = *(const float4*)&kp[(size_t)(q << 8)];
        kc[4 + q] = *(const float4*)&kp[(size_t)1024 + (q << 8)];
    }

    // ---- main loop: 128 chunks of 2 d-steps, barrier-free ----
    #pragma unroll 2
    for (int dc = 0; dc < 256; dc += 2) {
        const int dn = (dc + 2) & 255;           // wrap: last prefetch harmless
        float4 kn[8];
        #pragma unroll
        for (int q = 0; q < 4; ++q) {
            kn[q]     = *(const float4*)&kp[(size_t)dn * 1024 + (q << 8)];
            kn[4 + q] = *(const float4*)&kp[(size_t)(dn + 1) * 1024 + (q << 8)];
        }

        float2 qv[8];
        #pragma unroll
        for (int r = 0; r < 8; ++r)
            qv[r] = *(const float2*)&Qc[row0 + r][dc];

        #pragma unroll
        for (int r = 0; r < 8; ++r) {
            const float qa = qv[r].x;
            const float qb2 = qv[r].y;
            acc[r][0]  = fmaf(qa, kc[0].x, acc[r][0]);
            acc[r][1]  = fmaf(qa, kc[0].y, acc[r][1]);
            acc[r][2]  = fmaf(qa, kc[0].z, acc[r][2]);
            acc[r][3]  = fmaf(qa, kc[0].w, acc[r][3]);
            acc[r][4]  = fmaf(qa, kc[1].x, acc[r][4]);
            acc[r][5]  = fmaf(qa, kc[1].y, acc[r][5]);
            acc[r][6]  = fmaf(qa, kc[1].z, acc[r][6]);
            acc[r][7]  = fmaf(qa, kc[1].w, acc[r][7]);
            acc[r][8]  = fmaf(qa, kc[2].x, acc[r][8]);
            acc[r][9]  = fmaf(qa, kc[2].y, acc[r][9]);
            acc[r][10] = fmaf(qa, kc[2].z, acc[r][10]);
            acc[r][11] = fmaf(qa, kc[2].w, acc[r][11]);
            acc[r][12] = fmaf(qa, kc[3].x, acc[r][12]);
            acc[r][13] = fmaf(qa, kc[3].y, acc[r][13]);
            acc[r][14] = fmaf(qa, kc[3].z, acc[r][14]);
            acc[r][15] = fmaf(qa, kc[3].w, acc[r][15]);

            acc[r][0]  = fmaf(qb2, kc[4].x, acc[r][0]);
            acc[r][1]  = fmaf(qb2, kc[4].y, acc[r][1]);
            acc[r][2]  = fmaf(qb2, kc[4].z, acc[r][2]);
            acc[r][3]  = fmaf(qb2, kc[4].w, acc[r][3]);
            acc[r][4]  = fmaf(qb2, kc[5].x, acc[r][4]);
            acc[r][5]  = fmaf(qb2, kc[5].y, acc[r][5]);
            acc[r][6]  = fmaf(qb2, kc[5].z, acc[r][6]);
            acc[r][7]  = fmaf(qb2, kc[5].w, acc[r][7]);
            acc[r][8]  = fmaf(qb2, kc[6].x, acc[r][8]);
            acc[r][9]  = fmaf(qb2, kc[6].y, acc[r][9]);
            acc[r][10] = fmaf(qb2, kc[6].z, acc[r][10]);
            acc[r][11] = fmaf(qb2, kc[6].w, acc[r][11]);
            acc[r][12] = fmaf(qb2, kc[7].x, acc[r][12]);
            acc[r][13] = fmaf(qb2, kc[7].y, acc[r][13]);
            acc[r][14] = fmaf(qb2, kc[7].z, acc[r][14]);
            acc[r][15] = fmaf(qb2, kc[7].w, acc[r][15]);
        }

        #pragma unroll
        for (int q = 0; q < 8; ++q) kc[q] = kn[q];
    }

    // ---- epilogue: softmax stats + top-16 bitmask + single write pass ----
    const int growBase = b * 1024 + rowBase + row0;

    #pragma unroll 1
    for (int r = 0; r < 8; ++r) {
        float s[16];
        #pragma unroll
        for (int i = 0; i < 16; ++i) s[i] = acc[r][i] * 0.0625f;

        // row max (wave butterfly)
        float mx = s[0];
        #pragma unroll
        for (int i = 1; i < 16; ++i) mx = fmaxf(mx, s[i]);
        #pragma unroll
        for (int off = 32; off > 0; off >>= 1)
            mx = fmaxf(mx, __shfl_xor(mx, off));

        // softmax denominator
        float ls = 0.f;
        #pragma unroll
        for (int i = 0; i < 16; ++i) ls += __expf(s[i] - mx);
        #pragma unroll
        for (int off = 32; off > 0; off >>= 1)
            ls += __shfl_xor(ls, off);
        const float rZ = 1.0f / ls;

        // top-16 extraction on a destructible working copy; winners -> bitmask
        float wv[16];
        #pragma unroll
        for (int i = 0; i < 16; ++i) wv[i] = s[i];
        unsigned mask = 0u;

        #pragma unroll 1
        for (int j = 0; j < KNNK; ++j) {
            float bv  = wv[0];
            int   bsi = 0;
            #pragma unroll
            for (int i = 1; i < 16; ++i) {
                const bool c = wv[i] > bv;       // strict >, ascending slot scan
                bv  = c ? wv[i] : bv;
                bsi = c ? i     : bsi;
            }
            const int bmi = ((bsi >> 2) << 8) + (lane << 2) + (bsi & 3);
            const unsigned ub   = __float_as_uint(bv);
            const unsigned mono = ub ^ (unsigned)(((int)ub >> 31) | 0x80000000);
            const unsigned long long key =
                ((unsigned long long)mono << 32) | (unsigned)(~bmi);
            unsigned long long gk = key;
            #pragma unroll
            for (int off = 32; off > 0; off >>= 1) {
                const unsigned long long o = __shfl_xor(gk, off);
                gk = (o > gk) ? o : gk;
            }
            if (key == gk) {                     // unique winner lane
                mask |= (1u << bsi);
                #pragma unroll
                for (int i = 0; i < 16; ++i)
                    wv[i] = (i == bsi) ? -__builtin_inff() : wv[i];
            }
        }

        // single full-coverage write pass (each element written exactly once)
        float* orow = out + ((size_t)(growBase + r)) * 1024;
        #pragma unroll
        for (int o = 0; o < 4; ++o) {
            float4 v;
            v.x = ((mask >> ((o << 2) + 0)) & 1u) ? __expf(s[(o << 2) + 0] - mx) * rZ : 0.f;
            v.y = ((mask >> ((o << 2) + 1)) & 1u) ? __expf(s[(o << 2) + 1] - mx) * rZ : 0.f;
            v.z = ((mask >> ((o << 2) + 2)) & 1u) ? __expf(s[(o << 2) + 2] - mx) * rZ : 0.f;
            v.w = ((mask >> ((o << 2) + 3)) & 1u) ? __expf(s[(o << 2) + 3] - mx) * rZ : 0.f;
            *(float4*)&orow[(lane << 2) + (o << 8)] = v;
        }
    }
}

extern "C" void kernel_launch(void* const* d_in, const int* in_sizes, int n_in,
                              void* d_out, int out_size, void* d_ws, size_t ws_size,
                              hipStream_t stream)
{
    const float* x   = (const float*)d_in[0];
    const float* pos = (const float*)d_in[1];
    const float* wq  = (const float*)d_in[2];
    const float* bq  = (const float*)d_in[3];
    const float* wk  = (const float*)d_in[4];
    const float* bk  = (const float*)d_in[5];
    float* out = (float*)d_out;

    float* Qg  = (float*)d_ws;                    // 32 MB: [B*N, 256]
    float* Ktg = Qg + (size_t)NB * NN * ND;       // 32 MB: [B, 256, 1024]

    proj_kernel<<<dim3(4096), dim3(256), 0, stream>>>(x, pos, wq, bq, wk, bk, Qg, Ktg);
    adj_topk_kernel<<<dim3(1024), dim3(256), 0, stream>>>(Qg, Ktg, out);
}

// Round 3
// 491.443 us; speedup vs baseline: 1.4853x; 1.0721x over previous
//
#include <hip/hip_runtime.h>
#include <cstdint>
#include <cstddef>

#define NB 32
#define NN 1024
#define ND 256
#define KNNK 16

// ---------------------------------------------------------------------------
// Kernel A v3: fused positional-add + dual projection GEMM, TRANSPOSED out:
//   Qt [B, 256, 1024], Kt [B, 256, 1024]   (out[e][n] = sum_d h[n][d] w[e][d])
// Tile: 64 e x 64 n, 256 threads (tx=n microtile, ty=e microtile), 4x4 micro.
// Transposed layout makes both stores float4-coalesced AND lets kernel B read
// Q with wave-uniform (scalar) loads.
// ---------------------------------------------------------------------------
__global__ __launch_bounds__(256) void proj_kernel(
    const float* __restrict__ x, const float* __restrict__ pos,
    const float* __restrict__ wq, const float* __restrict__ bq,
    const float* __restrict__ wk, const float* __restrict__ bk,
    float* __restrict__ Qt, float* __restrict__ Kt)
{
    __shared__ __align__(16) float Hs[16][64];   // [d][n_local]
    __shared__ __align__(16) float Ws[16][64];   // [d][e_local]

    const int tid = threadIdx.x;
    const int tx = tid & 15;          // n microtile index
    const int ty = tid >> 4;          // e microtile index
    const int bm = blockIdx.x >> 3;   // 0..511 n tiles (b*16 + ntile)
    const int be = blockIdx.x & 7;    // 0..7 e tiles (0-3 -> Q, 4-7 -> K)
    const int nBase = bm << 6;        // global flattened n base (b*1024 + n0)
    const int b  = nBase >> 10;
    const int n0 = nBase & 1023;
    const int eBase = be << 6;
    const bool isQ = (eBase < 256);
    const float* __restrict__ W    = isQ ? wq : wk;
    const float* __restrict__ bias = isQ ? bq : bk;
    float* __restrict__ Og         = isQ ? Qt : Kt;
    const int e0 = isQ ? eBase : (eBase - 256);

    const int sr = tid >> 2;          // 0..63 (n or e index for staging)
    const int sd = (tid & 3) << 2;    // 0,4,8,12

    float acc[4][4];
    #pragma unroll
    for (int i = 0; i < 4; ++i)
        #pragma unroll
        for (int j = 0; j < 4; ++j) acc[i][j] = 0.0f;

    #pragma unroll 1
    for (int dc = 0; dc < 256; dc += 16) {
        const float4 xv = *(const float4*)&x[(size_t)(nBase + sr) * 256 + dc + sd];
        const float4 pv = *(const float4*)&pos[(size_t)(n0 + sr) * 256 + dc + sd];
        const float4 wv = *(const float4*)&W[(size_t)(e0 + sr) * 256 + dc + sd];
        __syncthreads();   // previous compute done reading LDS
        Hs[sd + 0][sr] = xv.x + pv.x;
        Hs[sd + 1][sr] = xv.y + pv.y;
        Hs[sd + 2][sr] = xv.z + pv.z;
        Hs[sd + 3][sr] = xv.w + pv.w;
        Ws[sd + 0][sr] = wv.x;
        Ws[sd + 1][sr] = wv.y;
        Ws[sd + 2][sr] = wv.z;
        Ws[sd + 3][sr] = wv.w;
        __syncthreads();
        #pragma unroll
        for (int d = 0; d < 16; ++d) {
            const float4 ev = *(const float4*)&Ws[d][ty << 2];   // e-dim (rows)
            const float4 nv = *(const float4*)&Hs[d][tx << 2];   // n-dim (cols)
            const float a4[4] = {ev.x, ev.y, ev.z, ev.w};
            const float b4[4] = {nv.x, nv.y, nv.z, nv.w};
            #pragma unroll
            for (int i = 0; i < 4; ++i)
                #pragma unroll
                for (int j = 0; j < 4; ++j)
                    acc[i][j] = fmaf(a4[i], b4[j], acc[i][j]);
        }
    }

    const float4 bv4 = *(const float4*)&bias[e0 + (ty << 2)];
    const float bb[4] = {bv4.x, bv4.y, bv4.z, bv4.w};
    #pragma unroll
    for (int i = 0; i < 4; ++i)
        #pragma unroll
        for (int j = 0; j < 4; ++j) acc[i][j] += bb[i];

    // coalesced transposed stores: row e = e0+4ty+i, cols n0+4tx..+3
    #pragma unroll
    for (int i = 0; i < 4; ++i) {
        float4 o;
        o.x = acc[i][0]; o.y = acc[i][1]; o.z = acc[i][2]; o.w = acc[i][3];
        *(float4*)&Og[(size_t)((b << 8) + e0 + (ty << 2) + i) * 1024 + n0 + (tx << 2)] = o;
    }
}

// ---------------------------------------------------------------------------
// Kernel B v3: scores + softmax + top-16, fused. One WG = (batch b, 32 rows).
// Main loop COLUMN-SPLIT: wave w owns cols [256w, 256w+256), lane owns 4
// consecutive cols; acc[32][4]. K L2 traffic = 1MB/block (4x less than v2).
// Q read with wave-uniform addresses from Qt -> s_load + scalar-operand FMA.
// Barrier-free main loop, 2-deep K prefetch.
// Epilogue: 4 passes x 8 rows through 32KB LDS to convert to row-ownership,
// then v2's proven selection + single coalesced write pass.
// ---------------------------------------------------------------------------
__global__ __launch_bounds__(256, 2) void adj_topk_kernel(
    const float* __restrict__ Qt, const float* __restrict__ Kt,
    float* __restrict__ out)
{
    __shared__ __align__(16) float Sc[8][1024];   // 32 KB score handoff

    const int tid  = threadIdx.x;
    const int lane = tid & 63;
    const int w    = tid >> 6;
    const int b       = blockIdx.x >> 5;
    const int rowBase = (blockIdx.x & 31) << 5;

    // Qt[b][d][rowBase + r]  (uniform per wave -> scalar loads)
    const float* __restrict__ Qb = Qt + (size_t)b * (256 * 1024) + rowBase;
    // lane's 4 columns of wave's quarter
    const float* __restrict__ kp = Kt + (size_t)b * (256 * 1024) + (w << 8) + (lane << 2);

    float acc[32][4];
    #pragma unroll
    for (int r = 0; r < 32; ++r)
        #pragma unroll
        for (int c = 0; c < 4; ++c) acc[r][c] = 0.0f;

    // ---- prefetch d=0,1 ----
    float4 k0 = *(const float4*)&kp[0];
    float4 k1 = *(const float4*)&kp[1024];

    // ---- main loop: 128 chunks of 2 d-steps, barrier-free ----
    #pragma unroll 2
    for (int d = 0; d < 256; d += 2) {
        const int dn = (d + 2) & 255;          // wrap: final prefetch harmless
        const float4 kn0 = *(const float4*)&kp[(size_t)dn * 1024];
        const float4 kn1 = *(const float4*)&kp[(size_t)(dn + 1) * 1024];

        const float* __restrict__ qrow0 = Qb + (size_t)d * 1024;
        const float* __restrict__ qrow1 = qrow0 + 1024;

        #pragma unroll
        for (int g = 0; g < 8; ++g) {
            const float4 q0 = *(const float4*)(qrow0 + (g << 2));  // uniform
            const float4 q1 = *(const float4*)(qrow1 + (g << 2));  // uniform
            const float q0a[4] = {q0.x, q0.y, q0.z, q0.w};
            const float q1a[4] = {q1.x, q1.y, q1.z, q1.w};
            #pragma unroll
            for (int j = 0; j < 4; ++j) {
                const int r = (g << 2) + j;
                acc[r][0] = fmaf(q0a[j], k0.x, acc[r][0]);
                acc[r][1] = fmaf(q0a[j], k0.y, acc[r][1]);
                acc[r][2] = fmaf(q0a[j], k0.z, acc[r][2]);
                acc[r][3] = fmaf(q0a[j], k0.w, acc[r][3]);
                acc[r][0] = fmaf(q1a[j], k1.x, acc[r][0]);
                acc[r][1] = fmaf(q1a[j], k1.y, acc[r][1]);
                acc[r][2] = fmaf(q1a[j], k1.z, acc[r][2]);
                acc[r][3] = fmaf(q1a[j], k1.w, acc[r][3]);
            }
        }
        k0 = kn0;
        k1 = kn1;
    }

    // ---- epilogue: 4 passes of 8 rows; LDS handoff -> row ownership ----
    const int growBase = b * 1024 + rowBase;

    #pragma unroll
    for (int p = 0; p < 4; ++p) {
        __syncthreads();            // prior pass's selection reads complete
        #pragma unroll
        for (int rr = 0; rr < 8; ++rr) {
            float4 v;
            v.x = acc[(p << 3) + rr][0];
            v.y = acc[(p << 3) + rr][1];
            v.z = acc[(p << 3) + rr][2];
            v.w = acc[(p << 3) + rr][3];
            *(float4*)&Sc[rr][(w << 8) + (lane << 2)] = v;
        }
        __syncthreads();

        // wave w selects rows 2w, 2w+1 of this pass
        #pragma unroll 1
        for (int t = 0; t < 2; ++t) {
            const int srw = (w << 1) + t;          // row within Sc
            float s[16];
            #pragma unroll
            for (int o = 0; o < 4; ++o) {
                const float4 sv = *(const float4*)&Sc[srw][(o << 8) + (lane << 2)];
                s[(o << 2) + 0] = sv.x * 0.0625f;
                s[(o << 2) + 1] = sv.y * 0.0625f;
                s[(o << 2) + 2] = sv.z * 0.0625f;
                s[(o << 2) + 3] = sv.w * 0.0625f;
            }

            // row max (wave butterfly)
            float mx = s[0];
            #pragma unroll
            for (int i = 1; i < 16; ++i) mx = fmaxf(mx, s[i]);
            #pragma unroll
            for (int off = 32; off > 0; off >>= 1)
                mx = fmaxf(mx, __shfl_xor(mx, off));

            // softmax denominator
            float ls = 0.f;
            #pragma unroll
            for (int i = 0; i < 16; ++i) ls += __expf(s[i] - mx);
            #pragma unroll
            for (int off = 32; off > 0; off >>= 1)
                ls += __shfl_xor(ls, off);
            const float rZ = 1.0f / ls;

            // top-16 extraction on a destructible copy; winners -> bitmask
            float wv[16];
            #pragma unroll
            for (int i = 0; i < 16; ++i) wv[i] = s[i];
            unsigned mask = 0u;

            #pragma unroll 1
            for (int j = 0; j < KNNK; ++j) {
                float bv  = wv[0];
                int   bsi = 0;
                #pragma unroll
                for (int i = 1; i < 16; ++i) {
                    const bool c = wv[i] > bv;   // strict >, ascending slot scan
                    bv  = c ? wv[i] : bv;
                    bsi = c ? i     : bsi;
                }
                const int bmi = ((bsi >> 2) << 8) + (lane << 2) + (bsi & 3);
                const unsigned ub   = __float_as_uint(bv);
                const unsigned mono = ub ^ (unsigned)(((int)ub >> 31) | 0x80000000);
                const unsigned long long key =
                    ((unsigned long long)mono << 32) | (unsigned)(~bmi);
                unsigned long long gk = key;
                #pragma unroll
                for (int off = 32; off > 0; off >>= 1) {
                    const unsigned long long o = __shfl_xor(gk, off);
                    gk = (o > gk) ? o : gk;
                }
                if (key == gk) {                 // unique winner lane
                    mask |= (1u << bsi);
                    #pragma unroll
                    for (int i = 0; i < 16; ++i)
                        wv[i] = (i == bsi) ? -__builtin_inff() : wv[i];
                }
            }

            // single full-coverage coalesced write pass for this row
            float* orow = out + ((size_t)(growBase + (p << 3) + srw)) * 1024;
            #pragma unroll
            for (int o = 0; o < 4; ++o) {
                float4 v;
                v.x = ((mask >> ((o << 2) + 0)) & 1u) ? __expf(s[(o << 2) + 0] - mx) * rZ : 0.f;
                v.y = ((mask >> ((o << 2) + 1)) & 1u) ? __expf(s[(o << 2) + 1] - mx) * rZ : 0.f;
                v.z = ((mask >> ((o << 2) + 2)) & 1u) ? __expf(s[(o << 2) + 2] - mx) * rZ : 0.f;
                v.w = ((mask >> ((o << 2) + 3)) & 1u) ? __expf(s[(o << 2) + 3] - mx) * rZ : 0.f;
                *(float4*)&orow[(lane << 2) + (o << 8)] = v;
            }
        }
    }
}

extern "C" void kernel_launch(void* const* d_in, const int* in_sizes, int n_in,
                              void* d_out, int out_size, void* d_ws, size_t ws_size,
                              hipStream_t stream)
{
    const float* x   = (const float*)d_in[0];
    const float* pos = (const float*)d_in[1];
    const float* wq  = (const float*)d_in[2];
    const float* bq  = (const float*)d_in[3];
    const float* wk  = (const float*)d_in[4];
    const float* bk  = (const float*)d_in[5];
    float* out = (float*)d_out;

    float* Qt = (float*)d_ws;                    // 32 MB: [B, 256, 1024]
    float* Kt = Qt + (size_t)NB * NN * ND;       // 32 MB: [B, 256, 1024]

    proj_kernel<<<dim3(4096), dim3(256), 0, stream>>>(x, pos, wq, bq, wk, bk, Qt, Kt);
    adj_topk_kernel<<<dim3(1024), dim3(256), 0, stream>>>(Qt, Kt, out);
}